// Round 6
// baseline (3446.614 us; speedup 1.0000x reference)
//
#include <hip/hip_runtime.h>
#include <math.h>

#define BB 2048
#define SS 96
#define DD 7
#define HH 64
#define H2 16
#define PAD 65   // [96][65] padded tiles
#define TPAD 97  // tkT [64][97]

__device__ __forceinline__ float sigm(float x) { return 1.0f / (1.0f + __expf(-x)); }
__device__ __forceinline__ float tanh_f(float x) { return 1.0f - 2.0f / (__expf(2.0f * x) + 1.0f); }
// broadcast lane l of v to all lanes via SGPR (VALU pipe, not LDS)
__device__ __forceinline__ float rl(float v, int l) {
    return __int_as_float(__builtin_amdgcn_readlane(__float_as_int(v), l));
}

// ---------------- Kernel 1: feature attention ----------------
__global__ __launch_bounds__(256) void k_feat(
    const float* __restrict__ x,
    const float* __restrict__ fv_w, const float* __restrict__ fv_b,
    const float* __restrict__ fk_w, const float* __restrict__ fk_b,
    const float* __restrict__ fq_w, const float* __restrict__ fq_b,
    float* __restrict__ fa_out)
{
    __shared__ float xs[SS * DD], vs[SS * DD], ks[SS * DD], qs[SS * DD];
    __shared__ float att[DD * DD];
    __shared__ float wv[DD * DD], wk[DD * DD], wq[DD * DD];
    __shared__ float bv[DD], bk[DD], bq[DD];
    const int b = blockIdx.x, t = threadIdx.x;
    const float* xb = x + (size_t)b * SS * DD;

    for (int idx = t; idx < SS * DD; idx += 256) xs[idx] = xb[idx];
    if (t < DD * DD) { wv[t] = fv_w[t]; wk[t] = fk_w[t]; wq[t] = fq_w[t]; }
    if (t < DD)      { bv[t] = fv_b[t]; bk[t] = fk_b[t]; bq[t] = fq_b[t]; }
    __syncthreads();

    for (int idx = t; idx < SS * DD; idx += 256) {
        int s = idx / DD, j = idx % DD;
        float a = bv[j];
        #pragma unroll
        for (int i = 0; i < DD; i++) a += xs[s * DD + i] * wv[j * DD + i];
        vs[idx] = a;
    }
    __syncthreads();
    for (int idx = t; idx < SS * DD; idx += 256) {
        int s = idx / DD, j = idx % DD;
        float a = bk[j];
        #pragma unroll
        for (int i = 0; i < DD; i++) a += (xs[s * DD + i] + vs[s * DD + i]) * wk[j * DD + i];
        ks[idx] = a;
    }
    __syncthreads();
    for (int idx = t; idx < SS * DD; idx += 256) {
        int s = idx / DD, j = idx % DD;
        float a = bq[j];
        #pragma unroll
        for (int i = 0; i < DD; i++) a += (xs[s * DD + i] + ks[s * DD + i]) * wq[j * DD + i];
        qs[idx] = a;
    }
    __syncthreads();
    if (t < DD * DD) {
        int i = t / DD, j = t % DD;
        float a = 0.0f;
        for (int s = 0; s < SS; s++) a += qs[s * DD + i] * ks[s * DD + j];
        att[t] = a;
    }
    __syncthreads();
    if (t < DD) {
        float m = -1e30f;
        #pragma unroll
        for (int j = 0; j < DD; j++) m = fmaxf(m, att[t * DD + j]);
        float e[DD]; float sum = 0.0f;
        #pragma unroll
        for (int j = 0; j < DD; j++) { e[j] = __expf(att[t * DD + j] - m); sum += e[j]; }
        float inv = 1.0f / sum;
        #pragma unroll
        for (int j = 0; j < DD; j++) att[t * DD + j] = e[j] * inv;
    }
    __syncthreads();
    for (int idx = t; idx < SS * DD; idx += 256) {
        int s = idx / DD, j = idx % DD;
        float a = xs[idx];
        #pragma unroll
        for (int i = 0; i < DD; i++) a += vs[s * DD + i] * att[i * DD + j];
        fa_out[(size_t)b * SS * DD + idx] = tanh_f(a);
    }
}

// ---------------- Kernel 2: bidirectional LSTM, 1 barrier/step ----------------
__global__ __launch_bounds__(512, 2) void k_bilstm(
    const float* __restrict__ fa,
    const float* __restrict__ wih_f, const float* __restrict__ whh_f,
    const float* __restrict__ bih_f, const float* __restrict__ bhh_f,
    const float* __restrict__ wih_b, const float* __restrict__ whh_b,
    const float* __restrict__ bih_b, const float* __restrict__ bhh_b,
    float* __restrict__ lo_out)
{
    __shared__ float fas[SS * DD];
    __shared__ float hbuf[2][HH];
    __shared__ float hs[2][SS][HH];

    const int b = blockIdx.x, t = threadIdx.x;
    const int lane = t & 63, w = t >> 6;
    const int dir = w >> 2, wq4 = w & 3;
    const int u = lane & 15;
    const int gi = lane >> 4;
    const int unit = 16 * wq4 + u;
    const int row = 64 * gi + unit;

    for (int idx = t; idx < SS * DD; idx += 512) fas[idx] = fa[(size_t)b * SS * DD + idx];

    const float* whh = dir ? whh_b : whh_f;
    const float* wih = dir ? wih_b : wih_f;
    float wr[HH];
    #pragma unroll
    for (int j = 0; j < HH; j++) wr[j] = whh[row * HH + j];
    float wx[DD];
    #pragma unroll
    for (int i = 0; i < DD; i++) wx[i] = wih[row * DD + i];
    const float bias = dir ? (bih_b[row] + bhh_b[row]) : (bih_f[row] + bhh_f[row]);

    if (t < 128) hbuf[t >> 6][t & 63] = 0.0f;
    __syncthreads();

    float c = 0.0f;
    for (int step = 0; step < SS; step++) {
        const int s = dir ? (SS - 1 - step) : step;
        float freg = fas[s * DD + (lane < DD ? lane : DD - 1)];
        float a = bias;
        #pragma unroll
        for (int i = 0; i < DD; i++) a += rl(freg, i) * wx[i];
        float hreg = hbuf[dir][lane];
        float b0 = 0.f, b1 = 0.f, b2 = 0.f, b3 = 0.f;
        #pragma unroll
        for (int j = 0; j < HH; j += 4) {
            b0 += rl(hreg, j)     * wr[j];
            b1 += rl(hreg, j + 1) * wr[j + 1];
            b2 += rl(hreg, j + 2) * wr[j + 2];
            b3 += rl(hreg, j + 3) * wr[j + 3];
        }
        a += (b0 + b1) + (b2 + b3);
        float iv = __shfl(a, u);
        float fv = __shfl(a, 16 + u);
        float gv = __shfl(a, 32 + u);
        float ov = __shfl(a, 48 + u);
        c = sigm(fv) * c + sigm(iv) * tanh_f(gv);
        float h = sigm(ov) * tanh_f(c);
        if (gi == 0) {
            hbuf[dir][unit] = h;
            hs[dir][s][unit] = h;
        }
        __syncthreads();
    }

    for (int idx = t; idx < SS * HH; idx += 512) {
        int s = idx >> 6, j = idx & 63;
        lo_out[(size_t)b * SS * HH + idx] = 0.5f * (hs[0][s][j] + hs[1][s][j]);
    }
}

// ---------------- Kernel 3: temporal attention + LSTM2 + fc ----------------
// All-wave-balanced phases, SGPR-weight fma density, readlane data broadcasts.
// LDS = loB(lo->q->to->xg2) + tkT(tk^T -> hsb) + tvB(tv) = 74,752 B -> 2 blocks/CU.
__global__ __launch_bounds__(512, 2) void k_temporal(
    const float* __restrict__ lo_g,
    const float* __restrict__ tv_w, const float* __restrict__ tv_b,
    const float* __restrict__ tk_w, const float* __restrict__ tk_b,
    const float* __restrict__ tq_w, const float* __restrict__ tq_b,
    const float* __restrict__ l2_wih, const float* __restrict__ l2_whh,
    const float* __restrict__ l2_bih, const float* __restrict__ l2_bhh,
    const float* __restrict__ fc_w, const float* __restrict__ fc_b,
    float* __restrict__ out)
{
    __shared__ float loB[SS * PAD];    // lo -> q -> 'to' -> xg2
    __shared__ float tkT[HH * TPAD];   // tk^T; later hsb[96*17]
    __shared__ float tvB[SS * PAD];    // tv

    const int b = blockIdx.x, t = threadIdx.x;
    const int lane = t & 63, w = t >> 6;
    float* hsb = tkT;                  // overlay: tkT dead after Phase B

    const float4* lo_src = (const float4*)(lo_g + (size_t)b * SS * HH);
    #pragma unroll
    for (int k = 0; k < 3; k++) {
        int idx4 = t + 512 * k;
        float4 v = lo_src[idx4];
        int s = idx4 >> 4, d = (idx4 & 15) * 4;
        loB[s * PAD + d]     = v.x;
        loB[s * PAD + d + 1] = v.y;
        loB[s * PAD + d + 2] = v.z;
        loB[s * PAD + d + 3] = v.w;
    }
    __syncthreads();

    // ---- Phase A': all 8 waves. Wave w owns j-slice [8w, 8w+8) of tv, tk, tq.
    //      lane = row (2 row-passes). SGPR weights, 1 fma/MAC. q -> regs.
    const int jbase = w * 8;
    float qout[2][8];
    #pragma unroll
    for (int rp = 0; rp < 2; rp++) {
        const int row = rp * 64 + lane;
        const bool act = (row < SS);
        if (act) {
            float lorow[HH];
            #pragma unroll
            for (int d = 0; d < HH; d++) lorow[d] = loB[row * PAD + d];
            #pragma unroll
            for (int jj = 0; jj < 8; jj++) {
                const int j = jbase + jj;
                float a0 = 0.f, a1 = 0.f, a2 = 0.f, a3 = 0.f;
                float b0 = 0.f, b1 = 0.f, b2 = 0.f, b3 = 0.f;
                float c0 = 0.f, c1 = 0.f, c2 = 0.f, c3 = 0.f;
                #pragma unroll
                for (int d = 0; d < HH; d += 4) {
                    a0 += lorow[d]     * tv_w[j * HH + d];
                    a1 += lorow[d + 1] * tv_w[j * HH + d + 1];
                    a2 += lorow[d + 2] * tv_w[j * HH + d + 2];
                    a3 += lorow[d + 3] * tv_w[j * HH + d + 3];
                    b0 += lorow[d]     * tk_w[j * HH + d];
                    b1 += lorow[d + 1] * tk_w[j * HH + d + 1];
                    b2 += lorow[d + 2] * tk_w[j * HH + d + 2];
                    b3 += lorow[d + 3] * tk_w[j * HH + d + 3];
                    c0 += lorow[d]     * tq_w[j * HH + d];
                    c1 += lorow[d + 1] * tq_w[j * HH + d + 1];
                    c2 += lorow[d + 2] * tq_w[j * HH + d + 2];
                    c3 += lorow[d + 3] * tq_w[j * HH + d + 3];
                }
                tvB[row * PAD + j]  = tv_b[j] + (a0 + a1) + (a2 + a3);
                tkT[j * TPAD + row] = tk_b[j] + (b0 + b1) + (b2 + b3);
                qout[rp][jj]        = tq_b[j] + (c0 + c1) + (c2 + c3);
            }
        }
    }
    __syncthreads();   // all lo reads done
    #pragma unroll
    for (int rp = 0; rp < 2; rp++) {
        const int row = rp * 64 + lane;
        if (row < SS) {
            #pragma unroll
            for (int jj = 0; jj < 8; jj++) loB[row * PAD + jbase + jj] = qout[rp][jj];
        }
    }
    __syncthreads();   // q visible

    // ---- Phase B: scores -> softmax -> PV -> 'to' (row-private in loB) ----
    for (int gi2 = 0; gi2 < 3; gi2++) {
        const int i0 = 4 * (w + 8 * gi2);
        float q0 = loB[(i0 + 0) * PAD + lane];
        float q1 = loB[(i0 + 1) * PAD + lane];
        float q2 = loB[(i0 + 2) * PAD + lane];
        float q3 = loB[(i0 + 3) * PAD + lane];
        const int p2i = 64 + (lane & 31);
        float a10 = 0.f, a11 = 0.f, a12 = 0.f, a13 = 0.f;
        float a20 = 0.f, a21 = 0.f, a22 = 0.f, a23 = 0.f;
        for (int f = 0; f < HH; f++) {
            float t1 = tkT[f * TPAD + lane];
            float t2 = tkT[f * TPAD + p2i];
            float s0 = rl(q0, f), s1 = rl(q1, f), s2 = rl(q2, f), s3 = rl(q3, f);
            a10 += s0 * t1; a20 += s0 * t2;
            a11 += s1 * t1; a21 += s1 * t2;
            a12 += s2 * t1; a22 += s2 * t2;
            a13 += s3 * t1; a23 += s3 * t2;
        }
        float p10, p11, p12, p13, p20, p21, p22, p23;
        {
            float m, s, e1, e2, ivv;
            m = fmaxf(a10, a20);
            #pragma unroll
            for (int o = 32; o; o >>= 1) m = fmaxf(m, __shfl_xor(m, o));
            e1 = __expf(a10 - m); e2 = __expf(a20 - m);
            s = e1 + ((lane < 32) ? e2 : 0.0f);
            #pragma unroll
            for (int o = 32; o; o >>= 1) s += __shfl_xor(s, o);
            ivv = 1.0f / s; p10 = e1 * ivv; p20 = e2 * ivv;

            m = fmaxf(a11, a21);
            #pragma unroll
            for (int o = 32; o; o >>= 1) m = fmaxf(m, __shfl_xor(m, o));
            e1 = __expf(a11 - m); e2 = __expf(a21 - m);
            s = e1 + ((lane < 32) ? e2 : 0.0f);
            #pragma unroll
            for (int o = 32; o; o >>= 1) s += __shfl_xor(s, o);
            ivv = 1.0f / s; p11 = e1 * ivv; p21 = e2 * ivv;

            m = fmaxf(a12, a22);
            #pragma unroll
            for (int o = 32; o; o >>= 1) m = fmaxf(m, __shfl_xor(m, o));
            e1 = __expf(a12 - m); e2 = __expf(a22 - m);
            s = e1 + ((lane < 32) ? e2 : 0.0f);
            #pragma unroll
            for (int o = 32; o; o >>= 1) s += __shfl_xor(s, o);
            ivv = 1.0f / s; p12 = e1 * ivv; p22 = e2 * ivv;

            m = fmaxf(a13, a23);
            #pragma unroll
            for (int o = 32; o; o >>= 1) m = fmaxf(m, __shfl_xor(m, o));
            e1 = __expf(a13 - m); e2 = __expf(a23 - m);
            s = e1 + ((lane < 32) ? e2 : 0.0f);
            #pragma unroll
            for (int o = 32; o; o >>= 1) s += __shfl_xor(s, o);
            ivv = 1.0f / s; p13 = e1 * ivv; p23 = e2 * ivv;
        }
        float o0 = 0.f, o1 = 0.f, o2 = 0.f, o3 = 0.f;
        for (int P = 0; P < 64; P++) {
            float tvv = tvB[P * PAD + lane];
            o0 += rl(p10, P) * tvv;
            o1 += rl(p11, P) * tvv;
            o2 += rl(p12, P) * tvv;
            o3 += rl(p13, P) * tvv;
        }
        for (int P = 0; P < 32; P++) {
            float tvv = tvB[(64 + P) * PAD + lane];
            o0 += rl(p20, P) * tvv;
            o1 += rl(p21, P) * tvv;
            o2 += rl(p22, P) * tvv;
            o3 += rl(p23, P) * tvv;
        }
        loB[(i0 + 0) * PAD + lane] = tanh_f(o0);
        loB[(i0 + 1) * PAD + lane] = tanh_f(o1);
        loB[(i0 + 2) * PAD + lane] = tanh_f(o2);
        loB[(i0 + 3) * PAD + lane] = tanh_f(o3);
    }
    __syncthreads();

    // ---- Phase C: xg2 = to @ l2_wih^T + biases. All 8 waves, wave w owns
    //      gate-slice [8w, 8w+8). lane = row, results staged in regs. ----
    {
        const int gbase = w * 8;
        float xout[2][8];
        #pragma unroll
        for (int rp = 0; rp < 2; rp++) {
            const int row = rp * 64 + lane;
            if (row < SS) {
                float toRow[HH];
                #pragma unroll
                for (int d = 0; d < HH; d++) toRow[d] = loB[row * PAD + d];
                #pragma unroll
                for (int jj = 0; jj < 8; jj++) {
                    const int gg = gbase + jj;
                    float a0 = 0.f, a1 = 0.f, a2 = 0.f, a3 = 0.f;
                    #pragma unroll
                    for (int d = 0; d < HH; d += 4) {
                        a0 += toRow[d]     * l2_wih[gg * HH + d];
                        a1 += toRow[d + 1] * l2_wih[gg * HH + d + 1];
                        a2 += toRow[d + 2] * l2_wih[gg * HH + d + 2];
                        a3 += toRow[d + 3] * l2_wih[gg * HH + d + 3];
                    }
                    xout[rp][jj] = l2_bih[gg] + l2_bhh[gg] + (a0 + a1) + (a2 + a3);
                }
            }
        }
        __syncthreads();   // all 'to' reads done
        #pragma unroll
        for (int rp = 0; rp < 2; rp++) {
            const int row = rp * 64 + lane;
            if (row < SS) {
                #pragma unroll
                for (int jj = 0; jj < 8; jj++) loB[row * PAD + gbase + jj] = xout[rp][jj];
            }
        }
    }
    __syncthreads();

    // ---- Phase D: LSTM2 scan (wave 0), hsb overlays tkT ----
    if (t < 64) {
        float whr[H2];
        #pragma unroll
        for (int j = 0; j < H2; j++) whr[j] = l2_whh[lane * H2 + j];
        const int myi = lane & 15;
        float h = 0.0f, c = 0.0f;
        for (int s = 0; s < SS; s++) {
            float a = loB[s * PAD + lane];
            #pragma unroll
            for (int j = 0; j < H2; j++) a += rl(h, j) * whr[j];
            float iv = __shfl(a, myi);
            float fv = __shfl(a, H2 + myi);
            float gv = __shfl(a, 2 * H2 + myi);
            float ov = __shfl(a, 3 * H2 + myi);
            c = sigm(fv) * c + sigm(iv) * tanh_f(gv);
            h = sigm(ov) * tanh_f(c);
            if (lane < H2) hsb[s * 17 + lane] = h;
        }
    }
    __syncthreads();

    // ---- Phase E: fc ----
    if (w < 2) {
        const int srow = w * 64 + lane;
        if (srow < SS) {
            float hreg[H2];
            #pragma unroll
            for (int j = 0; j < H2; j++) hreg[j] = hsb[srow * 17 + j];
            float* op = out + (size_t)b * SS * DD + srow * DD;
            for (int d = 0; d < DD; d++) {
                float a = fc_b[d];
                #pragma unroll
                for (int j = 0; j < H2; j++) a += hreg[j] * fc_w[d * H2 + j];
                op[d] = a;
            }
        }
    }
}

extern "C" void kernel_launch(void* const* d_in, const int* in_sizes, int n_in,
                              void* d_out, int out_size, void* d_ws, size_t ws_size,
                              hipStream_t stream) {
    const float* x     = (const float*)d_in[0];
    const float* fv_w  = (const float*)d_in[1];
    const float* fv_b  = (const float*)d_in[2];
    const float* fk_w  = (const float*)d_in[3];
    const float* fk_b  = (const float*)d_in[4];
    const float* fq_w  = (const float*)d_in[5];
    const float* fq_b  = (const float*)d_in[6];
    const float* l1f_wih = (const float*)d_in[7];
    const float* l1f_whh = (const float*)d_in[8];
    const float* l1f_bih = (const float*)d_in[9];
    const float* l1f_bhh = (const float*)d_in[10];
    const float* l1b_wih = (const float*)d_in[11];
    const float* l1b_whh = (const float*)d_in[12];
    const float* l1b_bih = (const float*)d_in[13];
    const float* l1b_bhh = (const float*)d_in[14];
    const float* tv_w  = (const float*)d_in[15];
    const float* tv_b  = (const float*)d_in[16];
    const float* tk_w  = (const float*)d_in[17];
    const float* tk_b  = (const float*)d_in[18];
    const float* tq_w  = (const float*)d_in[19];
    const float* tq_b  = (const float*)d_in[20];
    const float* l2_wih = (const float*)d_in[21];
    const float* l2_whh = (const float*)d_in[22];
    const float* l2_bih = (const float*)d_in[23];
    const float* l2_bhh = (const float*)d_in[24];
    const float* fc_w  = (const float*)d_in[25];
    const float* fc_b  = (const float*)d_in[26];

    float* fa = (float*)d_ws;                       // B*S*D floats
    float* lo = fa + (size_t)BB * SS * DD;          // B*S*H floats

    k_feat<<<BB, 256, 0, stream>>>(x, fv_w, fv_b, fk_w, fk_b, fq_w, fq_b, fa);
    k_bilstm<<<BB, 512, 0, stream>>>(fa,
        l1f_wih, l1f_whh, l1f_bih, l1f_bhh,
        l1b_wih, l1b_whh, l1b_bih, l1b_bhh, lo);
    k_temporal<<<BB, 512, 0, stream>>>(lo,
        tv_w, tv_b, tk_w, tk_b, tq_w, tq_b,
        l2_wih, l2_whh, l2_bih, l2_bhh, fc_w, fc_b,
        (float*)d_out);
}

// Round 7
// 960.934 us; speedup vs baseline: 3.5867x; 3.5867x over previous
//
#include <hip/hip_runtime.h>
#include <math.h>

#define BB 2048
#define SS 96
#define DD 7
#define HH 64
#define H2 16
#define LSTR 68    // loB row stride (fp32): 68*4=272B = 17*16 -> b128-aligned rows
#define HSTR 104   // f16 tile row stride: 104*2=208B = 13*16 -> b128-aligned rows

typedef _Float16 f16x8 __attribute__((ext_vector_type(8)));
typedef float f32x4 __attribute__((ext_vector_type(4)));

__device__ __forceinline__ float sigm(float x) { return 1.0f / (1.0f + __expf(-x)); }
__device__ __forceinline__ float tanh_f(float x) { return 1.0f - 2.0f / (__expf(2.0f * x) + 1.0f); }
__device__ __forceinline__ float rl(float v, int l) {
    return __int_as_float(__builtin_amdgcn_readlane(__float_as_int(v), l));
}
// load 8 consecutive fp32 (16B-aligned) and convert to an f16x8 A/B fragment
__device__ __forceinline__ f16x8 frag_from_f32(const float* base) {
    const float4* p = (const float4*)base;
    float4 a = p[0], b = p[1];
    f16x8 r;
    r[0] = (_Float16)a.x; r[1] = (_Float16)a.y; r[2] = (_Float16)a.z; r[3] = (_Float16)a.w;
    r[4] = (_Float16)b.x; r[5] = (_Float16)b.y; r[6] = (_Float16)b.z; r[7] = (_Float16)b.w;
    return r;
}

// ---------------- Kernel 1: feature attention (unchanged) ----------------
__global__ __launch_bounds__(256) void k_feat(
    const float* __restrict__ x,
    const float* __restrict__ fv_w, const float* __restrict__ fv_b,
    const float* __restrict__ fk_w, const float* __restrict__ fk_b,
    const float* __restrict__ fq_w, const float* __restrict__ fq_b,
    float* __restrict__ fa_out)
{
    __shared__ float xs[SS * DD], vs[SS * DD], ks[SS * DD], qs[SS * DD];
    __shared__ float att[DD * DD];
    __shared__ float wv[DD * DD], wk[DD * DD], wq[DD * DD];
    __shared__ float bv[DD], bk[DD], bq[DD];
    const int b = blockIdx.x, t = threadIdx.x;
    const float* xb = x + (size_t)b * SS * DD;

    for (int idx = t; idx < SS * DD; idx += 256) xs[idx] = xb[idx];
    if (t < DD * DD) { wv[t] = fv_w[t]; wk[t] = fk_w[t]; wq[t] = fq_w[t]; }
    if (t < DD)      { bv[t] = fv_b[t]; bk[t] = fk_b[t]; bq[t] = fq_b[t]; }
    __syncthreads();

    for (int idx = t; idx < SS * DD; idx += 256) {
        int s = idx / DD, j = idx % DD;
        float a = bv[j];
        #pragma unroll
        for (int i = 0; i < DD; i++) a += xs[s * DD + i] * wv[j * DD + i];
        vs[idx] = a;
    }
    __syncthreads();
    for (int idx = t; idx < SS * DD; idx += 256) {
        int s = idx / DD, j = idx % DD;
        float a = bk[j];
        #pragma unroll
        for (int i = 0; i < DD; i++) a += (xs[s * DD + i] + vs[s * DD + i]) * wk[j * DD + i];
        ks[idx] = a;
    }
    __syncthreads();
    for (int idx = t; idx < SS * DD; idx += 256) {
        int s = idx / DD, j = idx % DD;
        float a = bq[j];
        #pragma unroll
        for (int i = 0; i < DD; i++) a += (xs[s * DD + i] + ks[s * DD + i]) * wq[j * DD + i];
        qs[idx] = a;
    }
    __syncthreads();
    if (t < DD * DD) {
        int i = t / DD, j = t % DD;
        float a = 0.0f;
        for (int s = 0; s < SS; s++) a += qs[s * DD + i] * ks[s * DD + j];
        att[t] = a;
    }
    __syncthreads();
    if (t < DD) {
        float m = -1e30f;
        #pragma unroll
        for (int j = 0; j < DD; j++) m = fmaxf(m, att[t * DD + j]);
        float e[DD]; float sum = 0.0f;
        #pragma unroll
        for (int j = 0; j < DD; j++) { e[j] = __expf(att[t * DD + j] - m); sum += e[j]; }
        float inv = 1.0f / sum;
        #pragma unroll
        for (int j = 0; j < DD; j++) att[t * DD + j] = e[j] * inv;
    }
    __syncthreads();
    for (int idx = t; idx < SS * DD; idx += 256) {
        int s = idx / DD, j = idx % DD;
        float a = xs[idx];
        #pragma unroll
        for (int i = 0; i < DD; i++) a += vs[s * DD + i] * att[i * DD + j];
        fa_out[(size_t)b * SS * DD + idx] = tanh_f(a);
    }
}

// ---------------- Kernel 2: bidirectional LSTM (unchanged from R5) ----------------
__global__ __launch_bounds__(512, 2) void k_bilstm(
    const float* __restrict__ fa,
    const float* __restrict__ wih_f, const float* __restrict__ whh_f,
    const float* __restrict__ bih_f, const float* __restrict__ bhh_f,
    const float* __restrict__ wih_b, const float* __restrict__ whh_b,
    const float* __restrict__ bih_b, const float* __restrict__ bhh_b,
    float* __restrict__ lo_out)
{
    __shared__ float fas[SS * DD];
    __shared__ float hbuf[2][HH];
    __shared__ float hs[2][SS][HH];

    const int b = blockIdx.x, t = threadIdx.x;
    const int lane = t & 63, w = t >> 6;
    const int dir = w >> 2, wq4 = w & 3;
    const int u = lane & 15;
    const int gi = lane >> 4;
    const int unit = 16 * wq4 + u;
    const int row = 64 * gi + unit;

    for (int idx = t; idx < SS * DD; idx += 512) fas[idx] = fa[(size_t)b * SS * DD + idx];

    const float* whh = dir ? whh_b : whh_f;
    const float* wih = dir ? wih_b : wih_f;
    float wr[HH];
    #pragma unroll
    for (int j = 0; j < HH; j++) wr[j] = whh[row * HH + j];
    float wx[DD];
    #pragma unroll
    for (int i = 0; i < DD; i++) wx[i] = wih[row * DD + i];
    const float bias = dir ? (bih_b[row] + bhh_b[row]) : (bih_f[row] + bhh_f[row]);

    if (t < 128) hbuf[t >> 6][t & 63] = 0.0f;
    __syncthreads();

    float c = 0.0f;
    for (int step = 0; step < SS; step++) {
        const int s = dir ? (SS - 1 - step) : step;
        float freg = fas[s * DD + (lane < DD ? lane : DD - 1)];
        float a = bias;
        #pragma unroll
        for (int i = 0; i < DD; i++) a += rl(freg, i) * wx[i];
        float hreg = hbuf[dir][lane];
        float b0 = 0.f, b1 = 0.f, b2 = 0.f, b3 = 0.f;
        #pragma unroll
        for (int j = 0; j < HH; j += 4) {
            b0 += rl(hreg, j)     * wr[j];
            b1 += rl(hreg, j + 1) * wr[j + 1];
            b2 += rl(hreg, j + 2) * wr[j + 2];
            b3 += rl(hreg, j + 3) * wr[j + 3];
        }
        a += (b0 + b1) + (b2 + b3);
        float iv = __shfl(a, u);
        float fv = __shfl(a, 16 + u);
        float gv = __shfl(a, 32 + u);
        float ov = __shfl(a, 48 + u);
        c = sigm(fv) * c + sigm(iv) * tanh_f(gv);
        float h = sigm(ov) * tanh_f(c);
        if (gi == 0) {
            hbuf[dir][unit] = h;
            hs[dir][s][unit] = h;
        }
        __syncthreads();
    }

    for (int idx = t; idx < SS * HH; idx += 512) {
        int s = idx >> 6, j = idx & 63;
        lo_out[(size_t)b * SS * HH + idx] = 0.5f * (hs[0][s][j] + hs[1][s][j]);
    }
}

// ---------------- Kernel 3: temporal attention via MFMA f16 + LSTM2 + fc ----------------
// MFMA 16x16x32_f16 layouts (guide-verified):
//   A[m = lane&15][k = quad*8 + j],  B[n = lane&15][k = quad*8 + j],
//   C/D[row = quad*4 + reg][col = lane&15]
// Buffers sized so every fragment load is one ds_read_b128.
// LDS: loB fp32[96][68] + qB/pB f16[96][104] + tkS f16[96][104] + tvT f16[64][104]
//      = 79,360 B -> 2 blocks/CU. hsb overlays tvT after PV.
__global__ __launch_bounds__(512, 2) void k_temporal(
    const float* __restrict__ lo_g,
    const float* __restrict__ tv_w, const float* __restrict__ tv_b,
    const float* __restrict__ tk_w, const float* __restrict__ tk_b,
    const float* __restrict__ tq_w, const float* __restrict__ tq_b,
    const float* __restrict__ l2_wih, const float* __restrict__ l2_whh,
    const float* __restrict__ l2_bih, const float* __restrict__ l2_bhh,
    const float* __restrict__ fc_w, const float* __restrict__ fc_b,
    float* __restrict__ out)
{
    __shared__ float loB[SS * LSTR];        // lo -> 'to' -> xg2
    __shared__ _Float16 qB[SS * HSTR];      // q[s][f]; later p[s][P]
    __shared__ _Float16 tkS[SS * HSTR];     // tk[s][f]
    __shared__ _Float16 tvT[HH * HSTR];     // tv^T[d][P]; later hsb fp32[96*17]

    const int b = blockIdx.x, t = threadIdx.x;
    const int lane = t & 63, w = t >> 6;
    const int col = lane & 15, quad = lane >> 4;

    // ---- fill loB from global (float4) ----
    const float4* lo_src = (const float4*)(lo_g + (size_t)b * SS * HH);
    #pragma unroll
    for (int k = 0; k < 3; k++) {
        int idx4 = t + 512 * k;            // [0,1536)
        float4 v = lo_src[idx4];
        int s = idx4 >> 4, d = (idx4 & 15) * 4;
        loB[s * LSTR + d]     = v.x;
        loB[s * LSTR + d + 1] = v.y;
        loB[s * LSTR + d + 2] = v.z;
        loB[s * LSTR + d + 3] = v.w;
    }
    __syncthreads();

    // ---- Projections tv/tk/tq: 3 x (6 mt x 4 nt) tiles = 72 jobs, 9 per wave ----
    for (int i = 0; i < 9; i++) {
        const int flat = w + 8 * i;
        const int proj = flat / 24, rem = flat % 24;
        const int mt = rem >> 2, nt = rem & 3;
        const float* wmat = (proj == 0) ? tv_w : (proj == 1) ? tk_w : tq_w;
        const float* bvec = (proj == 0) ? tv_b : (proj == 1) ? tk_b : tq_b;
        const int j = 16 * nt + col;        // output feature (B n-index)
        f32x4 acc = {0.f, 0.f, 0.f, 0.f};
        #pragma unroll
        for (int kc = 0; kc < 2; kc++) {
            f16x8 a  = frag_from_f32(loB + (16 * mt + col) * LSTR + kc * 32 + quad * 8);
            f16x8 bb = frag_from_f32(wmat + j * HH + kc * 32 + quad * 8);
            acc = __builtin_amdgcn_mfma_f32_16x16x32_f16(a, bb, acc, 0, 0, 0);
        }
        const float bj = bvec[j];
        #pragma unroll
        for (int r = 0; r < 4; r++) {
            const float v = acc[r] + bj;
            const int row = 16 * mt + quad * 4 + r;   // seq position
            if (proj == 0)      tvT[j * HSTR + row] = (_Float16)v;  // tv^T[d][P]
            else if (proj == 1) tkS[row * HSTR + j] = (_Float16)v;  // tk[s][f]
            else                qB[row * HSTR + j]  = (_Float16)v;  // q[s][f]
        }
    }
    __syncthreads();

    // ---- scores -> softmax -> P -> PV -> 'to' : wave w<6 owns row-tile mt=w ----
    if (w < 6) {
        const int mt = w;
        // A-fragments of q (row-tile mt), K=64 -> 2 chunks
        f16x8 aq0 = *(const f16x8*)(qB + (16 * mt + col) * HSTR + quad * 8);
        f16x8 aq1 = *(const f16x8*)(qB + (16 * mt + col) * HSTR + 32 + quad * 8);
        f32x4 sc[6];
        #pragma unroll
        for (int nt = 0; nt < 6; nt++) {
            f32x4 acc = {0.f, 0.f, 0.f, 0.f};
            f16x8 b0 = *(const f16x8*)(tkS + (16 * nt + col) * HSTR + quad * 8);
            f16x8 b1 = *(const f16x8*)(tkS + (16 * nt + col) * HSTR + 32 + quad * 8);
            acc = __builtin_amdgcn_mfma_f32_16x16x32_f16(aq0, b0, acc, 0, 0, 0);
            acc = __builtin_amdgcn_mfma_f32_16x16x32_f16(aq1, b1, acc, 0, 0, 0);
            sc[nt] = acc;
        }
        // softmax per row r (row = quad*4+r spans this quad's 16 lanes x 6 tiles)
        #pragma unroll
        for (int r = 0; r < 4; r++) {
            float m = sc[0][r];
            #pragma unroll
            for (int nt = 1; nt < 6; nt++) m = fmaxf(m, sc[nt][r]);
            #pragma unroll
            for (int o = 1; o < 16; o <<= 1) m = fmaxf(m, __shfl_xor(m, o));
            float e[6]; float sum = 0.0f;
            #pragma unroll
            for (int nt = 0; nt < 6; nt++) { e[nt] = __expf(sc[nt][r] - m); sum += e[nt]; }
            #pragma unroll
            for (int o = 1; o < 16; o <<= 1) sum += __shfl_xor(sum, o);
            const float inv = 1.0f / sum;
            const int row = 16 * mt + quad * 4 + r;
            #pragma unroll
            for (int nt = 0; nt < 6; nt++)
                qB[row * HSTR + 16 * nt + col] = (_Float16)(e[nt] * inv);  // p[s][P]
        }
        // PV: A = p (row-tile mt, K=96 -> 3 chunks), B = tvT[d][P]
        f16x8 pa0 = *(const f16x8*)(qB + (16 * mt + col) * HSTR + quad * 8);
        f16x8 pa1 = *(const f16x8*)(qB + (16 * mt + col) * HSTR + 32 + quad * 8);
        f16x8 pa2 = *(const f16x8*)(qB + (16 * mt + col) * HSTR + 64 + quad * 8);
        #pragma unroll
        for (int nt = 0; nt < 4; nt++) {
            f32x4 acc = {0.f, 0.f, 0.f, 0.f};
            const _Float16* tvrow = tvT + (16 * nt + col) * HSTR;
            acc = __builtin_amdgcn_mfma_f32_16x16x32_f16(pa0, *(const f16x8*)(tvrow + quad * 8), acc, 0, 0, 0);
            acc = __builtin_amdgcn_mfma_f32_16x16x32_f16(pa1, *(const f16x8*)(tvrow + 32 + quad * 8), acc, 0, 0, 0);
            acc = __builtin_amdgcn_mfma_f32_16x16x32_f16(pa2, *(const f16x8*)(tvrow + 64 + quad * 8), acc, 0, 0, 0);
            #pragma unroll
            for (int r = 0; r < 4; r++)
                loB[(16 * mt + quad * 4 + r) * LSTR + 16 * nt + col] = tanh_f(acc[r]);
        }
    }
    __syncthreads();

    // ---- xg2 = to @ l2_wih^T + biases: 24 tiles, 3 per wave; stage, barrier, write ----
    {
        f32x4 xacc[3];
        #pragma unroll
        for (int i = 0; i < 3; i++) {
            const int flat = w + 8 * i;      // 0..23
            const int mt = flat >> 2, nt = flat & 3;
            const int g = 16 * nt + col;
            f32x4 acc = {0.f, 0.f, 0.f, 0.f};
            #pragma unroll
            for (int kc = 0; kc < 2; kc++) {
                f16x8 a  = frag_from_f32(loB + (16 * mt + col) * LSTR + kc * 32 + quad * 8);
                f16x8 bb = frag_from_f32(l2_wih + g * HH + kc * 32 + quad * 8);
                acc = __builtin_amdgcn_mfma_f32_16x16x32_f16(a, bb, acc, 0, 0, 0);
            }
            const float bg = l2_bih[g] + l2_bhh[g];
            #pragma unroll
            for (int r = 0; r < 4; r++) acc[r] += bg;
            xacc[i] = acc;
        }
        __syncthreads();
        #pragma unroll
        for (int i = 0; i < 3; i++) {
            const int flat = w + 8 * i;
            const int mt = flat >> 2, nt = flat & 3;
            const int g = 16 * nt + col;
            #pragma unroll
            for (int r = 0; r < 4; r++)
                loB[(16 * mt + quad * 4 + r) * LSTR + g] = xacc[i][r];
        }
    }
    __syncthreads();

    // ---- LSTM2 scan (wave 0); hsb overlays tvT ----
    float* hsb = (float*)tvT;
    if (t < 64) {
        float whr[H2];
        #pragma unroll
        for (int j = 0; j < H2; j++) whr[j] = l2_whh[lane * H2 + j];
        const int myi = lane & 15;
        float h = 0.0f, c = 0.0f;
        for (int s = 0; s < SS; s++) {
            float a = loB[s * LSTR + lane];
            #pragma unroll
            for (int j = 0; j < H2; j++) a += rl(h, j) * whr[j];
            float iv = __shfl(a, myi);
            float fv = __shfl(a, H2 + myi);
            float gv = __shfl(a, 2 * H2 + myi);
            float ov = __shfl(a, 3 * H2 + myi);
            c = sigm(fv) * c + sigm(iv) * tanh_f(gv);
            h = sigm(ov) * tanh_f(c);
            if (lane < H2) hsb[s * 17 + lane] = h;
        }
    }
    __syncthreads();

    // ---- fc ----
    if (w < 2) {
        const int srow = w * 64 + lane;
        if (srow < SS) {
            float hreg[H2];
            #pragma unroll
            for (int j = 0; j < H2; j++) hreg[j] = hsb[srow * 17 + j];
            float* op = out + (size_t)b * SS * DD + srow * DD;
            for (int d = 0; d < DD; d++) {
                float a = fc_b[d];
                #pragma unroll
                for (int j = 0; j < H2; j++) a += hreg[j] * fc_w[d * H2 + j];
                op[d] = a;
            }
        }
    }
}

extern "C" void kernel_launch(void* const* d_in, const int* in_sizes, int n_in,
                              void* d_out, int out_size, void* d_ws, size_t ws_size,
                              hipStream_t stream) {
    const float* x     = (const float*)d_in[0];
    const float* fv_w  = (const float*)d_in[1];
    const float* fv_b  = (const float*)d_in[2];
    const float* fk_w  = (const float*)d_in[3];
    const float* fk_b  = (const float*)d_in[4];
    const float* fq_w  = (const float*)d_in[5];
    const float* fq_b  = (const float*)d_in[6];
    const float* l1f_wih = (const float*)d_in[7];
    const float* l1f_whh = (const float*)d_in[8];
    const float* l1f_bih = (const float*)d_in[9];
    const float* l1f_bhh = (const float*)d_in[10];
    const float* l1b_wih = (const float*)d_in[11];
    const float* l1b_whh = (const float*)d_in[12];
    const float* l1b_bih = (const float*)d_in[13];
    const float* l1b_bhh = (const float*)d_in[14];
    const float* tv_w  = (const float*)d_in[15];
    const float* tv_b  = (const float*)d_in[16];
    const float* tk_w  = (const float*)d_in[17];
    const float* tk_b  = (const float*)d_in[18];
    const float* tq_w  = (const float*)d_in[19];
    const float* tq_b  = (const float*)d_in[20];
    const float* l2_wih = (const float*)d_in[21];
    const float* l2_whh = (const float*)d_in[22];
    const float* l2_bih = (const float*)d_in[23];
    const float* l2_bhh = (const float*)d_in[24];
    const float* fc_w  = (const float*)d_in[25];
    const float* fc_b  = (const float*)d_in[26];

    float* fa = (float*)d_ws;                       // B*S*D floats
    float* lo = fa + (size_t)BB * SS * DD;          // B*S*H floats

    k_feat<<<BB, 256, 0, stream>>>(x, fv_w, fv_b, fk_w, fk_b, fq_w, fq_b, fa);
    k_bilstm<<<BB, 512, 0, stream>>>(fa,
        l1f_wih, l1f_whh, l1f_bih, l1f_bhh,
        l1b_wih, l1b_whh, l1b_bih, l1b_bhh, lo);
    k_temporal<<<BB, 512, 0, stream>>>(lo,
        tv_w, tv_b, tk_w, tk_b, tq_w, tq_b,
        l2_wih, l2_whh, l2_bih, l2_bhh, fc_w, fc_b,
        (float*)d_out);
}